// Round 5
// baseline (398.392 us; speedup 1.0000x reference)
//
#include <hip/hip_runtime.h>
#include <hip/hip_bf16.h>
#include <math.h>

#define NHEADS 16
#define HDIM   64
#define BATCH  2
#define SEQLEN 2048
#define DIMSZ  1024

typedef _Float16 f16x8 __attribute__((ext_vector_type(8)));
typedef float    f32x4 __attribute__((ext_vector_type(4)));
typedef unsigned short u16x8 __attribute__((ext_vector_type(8)));

__device__ __forceinline__ float rope_theta(int c) {
    int i = c & 31;
    return (float)pow(10000.0, -(double)i / 32.0);
}
__device__ __forceinline__ unsigned short f16u(float f) {
    _Float16 h = (_Float16)f;
    return *reinterpret_cast<unsigned short*>(&h);
}
__device__ __forceinline__ void async_copy16(const void* gsrc, void* lds) {
    __builtin_amdgcn_global_load_lds(
        (const __attribute__((address_space(1))) unsigned int*)gsrc,
        (__attribute__((address_space(3))) unsigned int*)lds, 16, 0, 0);
}

// ---------------------------------------------------------------------------
// prep: f32->f16 conversions (x, Wq|Wk|Wv concat, Wo), bias concat, rope tables
// ---------------------------------------------------------------------------
__global__ __launch_bounds__(256) void prep_kernel(
    const float* __restrict__ x, const float* __restrict__ Wq,
    const float* __restrict__ Wk, const float* __restrict__ Wv,
    const float* __restrict__ Wo, const float* __restrict__ bq,
    const float* __restrict__ bk, const float* __restrict__ bv,
    unsigned short* __restrict__ x16, unsigned short* __restrict__ Wqkv16,
    unsigned short* __restrict__ Wo16, float* __restrict__ biasqkv,
    float* __restrict__ ropeC, float* __restrict__ ropeS)
{
    const int NV = (4194304 + 4 * 1048576) / 8;   // 1,048,576 vec8 chunks
    int gid = blockIdx.x * 256 + threadIdx.x;
    for (int i = gid; i < NV; i += gridDim.x * 256) {
        long e = (long)i * 8;
        const float* src; unsigned short* dst; long off;
        if (e < 4194304)      { src = x;  dst = x16;              off = e; }
        else if (e < 5242880) { src = Wq; dst = Wqkv16;           off = e - 4194304; }
        else if (e < 6291456) { src = Wk; dst = Wqkv16 + 1048576; off = e - 5242880; }
        else if (e < 7340032) { src = Wv; dst = Wqkv16 + 2097152; off = e - 6291456; }
        else                  { src = Wo; dst = Wo16;             off = e - 7340032; }
        float4 v0 = *reinterpret_cast<const float4*>(src + off);
        float4 v1 = *reinterpret_cast<const float4*>(src + off + 4);
        u16x8 o;
        o[0] = f16u(v0.x); o[1] = f16u(v0.y); o[2] = f16u(v0.z); o[3] = f16u(v0.w);
        o[4] = f16u(v1.x); o[5] = f16u(v1.y); o[6] = f16u(v1.z); o[7] = f16u(v1.w);
        *reinterpret_cast<u16x8*>(dst + off) = o;
    }
    if (gid < 65536) {
        int npos = gid >> 5, j = gid & 31;
        float f = (float)npos * rope_theta(j);
        ropeC[gid] = cosf(f);
        ropeS[gid] = sinf(f);
    }
    if (gid < 3072) {
        biasqkv[gid] = gid < 1024 ? bq[gid] : (gid < 2048 ? bk[gid - 1024] : bv[gid - 2048]);
    }
}

// ---------------------------------------------------------------------------
// Fused QKV GEMM + bias + (non-standard) rope.
//   Q, K -> (b,h,n,d) f16;  V -> TRANSPOSED (b,h,d,n) f16 for attn B-frags.
//   out[p]    = x[2p]*rope[2p]   - x[2p+1]*rope[2p+1]
//   out[p+32] = x[2p]*rope[2p+1] + x[2p+1]*rope[2p]
// where rope = [cos(th_0..31) | sin(th_0..31)] per position.
// ---------------------------------------------------------------------------
__global__ __launch_bounds__(256) void qkv_gemm_kernel(
    const unsigned short* __restrict__ A, const unsigned short* __restrict__ B,
    const float* __restrict__ bias, const float* __restrict__ ropeC,
    const float* __restrict__ ropeS, unsigned short* __restrict__ QKV)
{
    __shared__ __align__(16) _Float16 As[128][64];
    __shared__ __align__(16) _Float16 Bs[128][64];
    const int tid = threadIdx.x;
    const int w = tid >> 6, lane = tid & 63;
    const int g = lane >> 4, lx = lane & 15;
    const int wr = w >> 1, wc = w & 1;
    const int row0 = blockIdx.y * 128;
    const int col0 = blockIdx.x * 128;
    const unsigned short* Ab = A + (size_t)row0 * DIMSZ;
    const unsigned short* Bb = B + (size_t)col0 * DIMSZ;

    f32x4 acc[4][4] = {};
    for (int k0 = 0; k0 < DIMSZ; k0 += 64) {
        __syncthreads();
        #pragma unroll
        for (int i = 0; i < 4; ++i) {
            int idx = i * 256 + tid;
            int r = idx >> 3, cb = (idx & 7) * 8;
            async_copy16(Ab + (size_t)r * DIMSZ + k0 + cb,
                         (_Float16*)As + (size_t)(i * 256 + w * 64) * 8);
        }
        #pragma unroll
        for (int i = 0; i < 4; ++i) {
            int idx = i * 256 + tid;
            int r = idx >> 3, cb = (idx & 7) * 8;
            async_copy16(Bb + (size_t)r * DIMSZ + k0 + cb,
                         (_Float16*)Bs + (size_t)(i * 256 + w * 64) * 8);
        }
        __syncthreads();
        #pragma unroll
        for (int ks = 0; ks < 2; ++ks) {
            f16x8 af[4], bf[4];
            #pragma unroll
            for (int m = 0; m < 4; ++m)
                af[m] = *reinterpret_cast<const f16x8*>(&As[wr * 64 + m * 16 + lx][ks * 32 + g * 8]);
            #pragma unroll
            for (int n = 0; n < 4; ++n)
                bf[n] = *reinterpret_cast<const f16x8*>(&Bs[wc * 64 + n * 16 + lx][ks * 32 + g * 8]);
            #pragma unroll
            for (int m = 0; m < 4; ++m)
                #pragma unroll
                for (int n = 0; n < 4; ++n)
                    acc[m][n] = __builtin_amdgcn_mfma_f32_16x16x32_f16(af[m], bf[n], acc[m][n], 0, 0, 0);
        }
    }

    const int hcol0 = col0 + wc * 64;          // multiple of 64, one head
    const int proj  = hcol0 >> 10;
    const int hd    = (hcol0 & 1023) >> 6;
    float bsv[4];
    #pragma unroll
    for (int n = 0; n < 4; ++n) bsv[n] = bias[hcol0 + n * 16 + lx];

    #pragma unroll
    for (int m = 0; m < 4; ++m) {
        int rbase = row0 + wr * 64 + m * 16 + g * 4;
        #pragma unroll
        for (int r2 = 0; r2 < 4; ++r2) {
            int rglob = rbase + r2;
            int b = rglob >> 11, npos = rglob & (SEQLEN - 1);
            const float* rcp = ropeC + npos * 32;
            const float* rsp = ropeS + npos * 32;
            unsigned short* Orow = QKV +
                ((((size_t)proj * BATCH + b) * NHEADS + hd) * SEQLEN + npos) * HDIM;
            unsigned short* Vbase = QKV + 8388608 +
                (((size_t)b * NHEADS + hd) * HDIM) * SEQLEN + npos;
            #pragma unroll
            for (int n = 0; n < 4; ++n) {
                float v = acc[m][n][r2] + bsv[n];   // x[d], d = n*16+lx
                float o = __shfl_xor(v, 1);         // x[d^1]
                int d = n * 16 + lx;
                const float* tab = (d < 32) ? rcp : rsp;
                float Rd = tab[d & 31];             // rope[d]
                float Rp = tab[(d & 31) ^ 1];       // rope[d^1]
                float y;
                int outc;
                if (d & 1) { y = o * Rd + v * Rp; outc = (d >> 1) + 32; }
                else       { y = v * Rd - o * Rp; outc = d >> 1; }
                if (proj == 2)
                    Vbase[(size_t)outc * SEQLEN] = f16u(y);   // V^T: (b,h,d,n)
                else
                    Orow[outc] = f16u(y);
            }
        }
    }
}

// ---------------------------------------------------------------------------
// MFMA flash attention (f16), BARRIER-FREE main loop.
// 4 waves x 16 q-rows; K frags + V^T frags loaded DIRECT from global
// (L2-resident, 512KB per bh); LDS only for the per-wave P round-trip.
// Epilogue: -rope via tables, writes f16 Y (b,n,dim).
// ---------------------------------------------------------------------------
__global__ __launch_bounds__(256) void attn_mfma_kernel(
    const unsigned short* __restrict__ QKV, const float* __restrict__ ropeC,
    const float* __restrict__ ropeS, unsigned short* __restrict__ Y)
{
    __shared__ __align__(16) unsigned char smem[17408];   // P: 4x2KB; epi: [64][68]f32
    const int tid = threadIdx.x;
    const int w   = tid >> 6;
    const int l   = tid & 63;
    const int g   = l >> 4;
    const int lx  = l & 15;
    const int bh  = blockIdx.y;
    const int b   = bh >> 4;
    const int h   = bh & 15;
    const int q0  = blockIdx.x * 64;

    const unsigned short* Qb  = QKV + (size_t)bh * SEQLEN * HDIM;
    const unsigned short* Kb  = QKV + 4194304 + (size_t)bh * SEQLEN * HDIM;
    const unsigned short* Vtb = QKV + 8388608 + (size_t)bh * SEQLEN * HDIM;  // (d,n)

    f16x8 qf[2];
    {
        const unsigned short* src = Qb + (size_t)(q0 + w * 16 + lx) * HDIM + g * 8;
        qf[0] = *reinterpret_cast<const f16x8*>(src);
        qf[1] = *reinterpret_cast<const f16x8*>(src + 32);
    }

    f32x4 oacc[4] = {};
    float mrow[4] = {-1e30f, -1e30f, -1e30f, -1e30f};
    float lrow[4] = {0.f, 0.f, 0.f, 0.f};
    const int pbase = w * 2048;

    for (int kt = 0; kt < SEQLEN / 64; ++kt) {
        const int k0 = kt * 64;

        // ---- K fragments direct from global: kf[c] covers keys c*16+lx
        f16x8 kf0[4], kf1[4];
        #pragma unroll
        for (int c = 0; c < 4; ++c) {
            const unsigned short* kp = Kb + (size_t)(k0 + c * 16 + lx) * HDIM + g * 8;
            kf0[c] = *reinterpret_cast<const f16x8*>(kp);
            kf1[c] = *reinterpret_cast<const f16x8*>(kp + 32);
        }

        // ---- QK^T
        f32x4 sacc[4] = {};
        __builtin_amdgcn_s_setprio(1);
        #pragma unroll
        for (int c = 0; c < 4; ++c) {
            sacc[c] = __builtin_amdgcn_mfma_f32_16x16x32_f16(qf[0], kf0[c], sacc[c], 0, 0, 0);
            sacc[c] = __builtin_amdgcn_mfma_f32_16x16x32_f16(qf[1], kf1[c], sacc[c], 0, 0, 0);
        }
        __builtin_amdgcn_s_setprio(0);

        // ---- V^T fragments issued early (overlap softmax VALU)
        f16x8 vf[2][4];
        #pragma unroll
        for (int kc = 0; kc < 2; ++kc)
            #pragma unroll
            for (int c = 0; c < 4; ++c)
                vf[kc][c] = *reinterpret_cast<const f16x8*>(
                    Vtb + (size_t)(c * 16 + lx) * SEQLEN + k0 + kc * 32 + g * 8);

        // ---- online softmax (scale folded into exp)
        #pragma unroll
        for (int r = 0; r < 4; ++r) {
            float mx = fmaxf(fmaxf(sacc[0][r], sacc[1][r]), fmaxf(sacc[2][r], sacc[3][r]));
            #pragma unroll
            for (int mm = 1; mm < 16; mm <<= 1) mx = fmaxf(mx, __shfl_xor(mx, mm));
            float mnew = fmaxf(mrow[r], mx);
            float sc = __expf((mrow[r] - mnew) * 0.125f);
            mrow[r] = mnew;
            float p0 = __expf((sacc[0][r] - mnew) * 0.125f);
            float p1 = __expf((sacc[1][r] - mnew) * 0.125f);
            float p2 = __expf((sacc[2][r] - mnew) * 0.125f);
            float p3 = __expf((sacc[3][r] - mnew) * 0.125f);
            sacc[0][r] = p0; sacc[1][r] = p1; sacc[2][r] = p2; sacc[3][r] = p3;
            float sm = p0 + p1 + p2 + p3;
            #pragma unroll
            for (int mm = 1; mm < 16; mm <<= 1) sm += __shfl_xor(sm, mm);
            lrow[r] = lrow[r] * sc + sm;
            #pragma unroll
            for (int c2 = 0; c2 < 4; ++c2) oacc[c2][r] *= sc;
        }

        // ---- P -> per-wave LDS (swizzled), no cross-wave barrier needed
        #pragma unroll
        for (int c = 0; c < 4; ++c)
            #pragma unroll
            for (int r = 0; r < 4; ++r) {
                int q = g * 4 + r;
                int key = c * 16 + lx;
                *reinterpret_cast<_Float16*>(&smem[pbase + q * 128 + ((key * 2) ^ ((q & 7) << 4))]) = (_Float16)sacc[c][r];
            }
        asm volatile("s_waitcnt lgkmcnt(0)" ::: "memory");
        __builtin_amdgcn_sched_barrier(0);

        // ---- PV
        #pragma unroll
        for (int kc = 0; kc < 2; ++kc) {
            f16x8 pf = *reinterpret_cast<const f16x8*>(
                &smem[pbase + lx * 128 + ((kc * 64 + g * 16) ^ ((lx & 7) << 4))]);
            __builtin_amdgcn_s_setprio(1);
            #pragma unroll
            for (int c = 0; c < 4; ++c)
                oacc[c] = __builtin_amdgcn_mfma_f32_16x16x32_f16(pf, vf[kc][c], oacc[c], 0, 0, 0);
            __builtin_amdgcn_s_setprio(0);
        }
    }

    // ---- epilogue: normalize, stash O in LDS, -rope, store
    __syncthreads();
    float inv[4];
    #pragma unroll
    for (int r = 0; r < 4; ++r) inv[r] = 1.0f / lrow[r];
    float* OS = (float*)smem;   // [64][68]
    #pragma unroll
    for (int c = 0; c < 4; ++c)
        #pragma unroll
        for (int r = 0; r < 4; ++r)
            OS[(w * 16 + g * 4 + r) * 68 + c * 16 + lx] = oacc[c][r] * inv[r];
    __syncthreads();

    const int tx = tid & 15, ty = tid >> 4;
    const bool is_cos = (tx < 8);
    const int ji = (4 * tx) & 31;
    #pragma unroll
    for (int rep = 0; rep < 4; ++rep) {
        int row = ty + rep * 16;
        int q = q0 + row;
        f32x4 o = *reinterpret_cast<const f32x4*>(&OS[row * 68 + 4 * tx]);
        const float* tab = is_cos ? ropeC : ropeS;
        float4 R = *reinterpret_cast<const float4*>(&tab[q * 32 + ji]);
        float yp0 = -(o[0] * R.x - o[1] * R.y);
        float yp1 = -(o[2] * R.z - o[3] * R.w);
        float yq0 = -(o[0] * R.y + o[1] * R.x);
        float yq1 = -(o[2] * R.w + o[3] * R.z);
        unsigned short* dst = &Y[((size_t)b * SEQLEN + q) * DIMSZ + h * HDIM];
        unsigned lo = (unsigned)f16u(yp0) | ((unsigned)f16u(yp1) << 16);
        unsigned hi = (unsigned)f16u(yq0) | ((unsigned)f16u(yq1) << 16);
        *reinterpret_cast<unsigned*>(&dst[2 * tx])      = lo;
        *reinterpret_cast<unsigned*>(&dst[2 * tx + 32]) = hi;
    }
}

// ---------------------------------------------------------------------------
// Out GEMM: out[4096 x 1024] = Y16 @ Wo16^T + bo (f32 out)
// ---------------------------------------------------------------------------
__global__ __launch_bounds__(256) void out_gemm_kernel(
    const unsigned short* __restrict__ A, const unsigned short* __restrict__ B,
    const float* __restrict__ bias, float* __restrict__ Out)
{
    __shared__ __align__(16) _Float16 As[128][64];
    __shared__ __align__(16) _Float16 Bs[128][64];
    const int tid = threadIdx.x;
    const int w = tid >> 6, lane = tid & 63;
    const int g = lane >> 4, lx = lane & 15;
    const int wr = w >> 1, wc = w & 1;
    const int row0 = blockIdx.y * 128;
    const int col0 = blockIdx.x * 128;
    const unsigned short* Ab = A + (size_t)row0 * DIMSZ;
    const unsigned short* Bb = B + (size_t)col0 * DIMSZ;

    f32x4 acc[4][4] = {};
    for (int k0 = 0; k0 < DIMSZ; k0 += 64) {
        __syncthreads();
        #pragma unroll
        for (int i = 0; i < 4; ++i) {
            int idx = i * 256 + tid;
            int r = idx >> 3, cb = (idx & 7) * 8;
            async_copy16(Ab + (size_t)r * DIMSZ + k0 + cb,
                         (_Float16*)As + (size_t)(i * 256 + w * 64) * 8);
        }
        #pragma unroll
        for (int i = 0; i < 4; ++i) {
            int idx = i * 256 + tid;
            int r = idx >> 3, cb = (idx & 7) * 8;
            async_copy16(Bb + (size_t)r * DIMSZ + k0 + cb,
                         (_Float16*)Bs + (size_t)(i * 256 + w * 64) * 8);
        }
        __syncthreads();
        #pragma unroll
        for (int ks = 0; ks < 2; ++ks) {
            f16x8 af[4], bf[4];
            #pragma unroll
            for (int m = 0; m < 4; ++m)
                af[m] = *reinterpret_cast<const f16x8*>(&As[wr * 64 + m * 16 + lx][ks * 32 + g * 8]);
            #pragma unroll
            for (int n = 0; n < 4; ++n)
                bf[n] = *reinterpret_cast<const f16x8*>(&Bs[wc * 64 + n * 16 + lx][ks * 32 + g * 8]);
            #pragma unroll
            for (int m = 0; m < 4; ++m)
                #pragma unroll
                for (int n = 0; n < 4; ++n)
                    acc[m][n] = __builtin_amdgcn_mfma_f32_16x16x32_f16(af[m], bf[n], acc[m][n], 0, 0, 0);
        }
    }

    const int cb0 = col0 + wc * 64;
    float bsv[4];
    #pragma unroll
    for (int n = 0; n < 4; ++n) bsv[n] = bias[cb0 + n * 16 + lx];
    #pragma unroll
    for (int m = 0; m < 4; ++m) {
        int rbase = row0 + wr * 64 + m * 16 + g * 4;
        #pragma unroll
        for (int r2 = 0; r2 < 4; ++r2) {
            float* orow = Out + (size_t)(rbase + r2) * DIMSZ + cb0;
            #pragma unroll
            for (int n = 0; n < 4; ++n)
                orow[n * 16 + lx] = acc[m][n][r2] + bsv[n];
        }
    }
}

extern "C" void kernel_launch(void* const* d_in, const int* in_sizes, int n_in,
                              void* d_out, int out_size, void* d_ws, size_t ws_size,
                              hipStream_t stream) {
    const float* x  = (const float*)d_in[0];
    const float* Wq = (const float*)d_in[1];
    const float* bq = (const float*)d_in[2];
    const float* Wk = (const float*)d_in[3];
    const float* bk = (const float*)d_in[4];
    const float* Wv = (const float*)d_in[5];
    const float* bv = (const float*)d_in[6];
    const float* Wo = (const float*)d_in[7];
    const float* bo = (const float*)d_in[8];
    float* out = (float*)d_out;

    char* ws = (char*)d_ws;
    unsigned short* x16    = (unsigned short*)(ws);
    unsigned short* Wqkv16 = (unsigned short*)(ws + 8388608);
    unsigned short* Wo16   = (unsigned short*)(ws + 14680064);
    float* biasqkv         = (float*)(ws + 16777216);
    float* ropeC           = (float*)(ws + 16793600);
    float* ropeS           = (float*)(ws + 17055744);
    unsigned short* QKVw   = (unsigned short*)(ws + 17825792);
    unsigned short* Yw     = (unsigned short*)(ws + 42991616);

    dim3 blk(256);
    prep_kernel<<<dim3(2048), blk, 0, stream>>>(x, Wq, Wk, Wv, Wo, bq, bk, bv,
                                                x16, Wqkv16, Wo16, biasqkv, ropeC, ropeS);
    qkv_gemm_kernel<<<dim3(24, 32), blk, 0, stream>>>(x16, Wqkv16, biasqkv, ropeC, ropeS, QKVw);
    attn_mfma_kernel<<<dim3(SEQLEN / 64, BATCH * NHEADS), blk, 0, stream>>>(QKVw, ropeC, ropeS, Yw);
    out_gemm_kernel<<<dim3(8, 32), blk, 0, stream>>>(Yw, Wo16, bo, out);
}

// Round 6
// 191.726 us; speedup vs baseline: 2.0779x; 2.0779x over previous
//
#include <hip/hip_runtime.h>
#include <hip/hip_bf16.h>
#include <math.h>

#define NHEADS 16
#define HDIM   64
#define BATCH  2
#define SEQLEN 2048
#define DIMSZ  1024

typedef _Float16 f16x8 __attribute__((ext_vector_type(8)));
typedef float    f32x4 __attribute__((ext_vector_type(4)));
typedef unsigned short u16x8 __attribute__((ext_vector_type(8)));

__device__ __forceinline__ float rope_theta(int c) {
    int i = c & 31;
    return (float)pow(10000.0, -(double)i / 32.0);
}
__device__ __forceinline__ unsigned short f16u(float f) {
    _Float16 h = (_Float16)f;
    return *reinterpret_cast<unsigned short*>(&h);
}
__device__ __forceinline__ void async_copy16(const void* gsrc, void* lds) {
    __builtin_amdgcn_global_load_lds(
        (const __attribute__((address_space(1))) unsigned int*)gsrc,
        (__attribute__((address_space(3))) unsigned int*)lds, 16, 0, 0);
}

// ---------------------------------------------------------------------------
// prep: f32->f16 conversions (x, Wq|Wk|Wv concat, Wo), bias concat, rope tables
// ---------------------------------------------------------------------------
__global__ __launch_bounds__(256) void prep_kernel(
    const float* __restrict__ x, const float* __restrict__ Wq,
    const float* __restrict__ Wk, const float* __restrict__ Wv,
    const float* __restrict__ Wo, const float* __restrict__ bq,
    const float* __restrict__ bk, const float* __restrict__ bv,
    unsigned short* __restrict__ x16, unsigned short* __restrict__ Wqkv16,
    unsigned short* __restrict__ Wo16, float* __restrict__ biasqkv,
    float* __restrict__ ropeC, float* __restrict__ ropeS)
{
    const int NV = (4194304 + 4 * 1048576) / 8;   // 1,048,576 vec8 chunks
    int gid = blockIdx.x * 256 + threadIdx.x;
    for (int i = gid; i < NV; i += gridDim.x * 256) {
        long e = (long)i * 8;
        const float* src; unsigned short* dst; long off;
        if (e < 4194304)      { src = x;  dst = x16;              off = e; }
        else if (e < 5242880) { src = Wq; dst = Wqkv16;           off = e - 4194304; }
        else if (e < 6291456) { src = Wk; dst = Wqkv16 + 1048576; off = e - 5242880; }
        else if (e < 7340032) { src = Wv; dst = Wqkv16 + 2097152; off = e - 6291456; }
        else                  { src = Wo; dst = Wo16;             off = e - 7340032; }
        float4 v0 = *reinterpret_cast<const float4*>(src + off);
        float4 v1 = *reinterpret_cast<const float4*>(src + off + 4);
        u16x8 o;
        o[0] = f16u(v0.x); o[1] = f16u(v0.y); o[2] = f16u(v0.z); o[3] = f16u(v0.w);
        o[4] = f16u(v1.x); o[5] = f16u(v1.y); o[6] = f16u(v1.z); o[7] = f16u(v1.w);
        *reinterpret_cast<u16x8*>(dst + off) = o;
    }
    if (gid < 65536) {
        int npos = gid >> 5, j = gid & 31;
        float f = (float)npos * rope_theta(j);
        ropeC[gid] = cosf(f);
        ropeS[gid] = sinf(f);
    }
    if (gid < 3072) {
        biasqkv[gid] = gid < 1024 ? bq[gid] : (gid < 2048 ? bk[gid - 1024] : bv[gid - 2048]);
    }
}

// ---------------------------------------------------------------------------
// Fused QKV GEMM + bias + (non-standard) rope.
//   Q, K -> (b,h,n,d) f16;  V -> TRANSPOSED (b,h,d,n) f16 for attn B-frags.
//   out[p]    = x[2p]*rope[2p]   - x[2p+1]*rope[2p+1]
//   out[p+32] = x[2p]*rope[2p+1] + x[2p+1]*rope[2p]
// where rope = [cos(th_0..31) | sin(th_0..31)] per position.
// ---------------------------------------------------------------------------
__global__ __launch_bounds__(256) void qkv_gemm_kernel(
    const unsigned short* __restrict__ A, const unsigned short* __restrict__ B,
    const float* __restrict__ bias, const float* __restrict__ ropeC,
    const float* __restrict__ ropeS, unsigned short* __restrict__ QKV)
{
    __shared__ __align__(16) _Float16 As[128][64];
    __shared__ __align__(16) _Float16 Bs[128][64];
    const int tid = threadIdx.x;
    const int w = tid >> 6, lane = tid & 63;
    const int g = lane >> 4, lx = lane & 15;
    const int wr = w >> 1, wc = w & 1;
    const int row0 = blockIdx.y * 128;
    const int col0 = blockIdx.x * 128;
    const unsigned short* Ab = A + (size_t)row0 * DIMSZ;
    const unsigned short* Bb = B + (size_t)col0 * DIMSZ;

    f32x4 acc[4][4] = {};
    for (int k0 = 0; k0 < DIMSZ; k0 += 64) {
        __syncthreads();
        #pragma unroll
        for (int i = 0; i < 4; ++i) {
            int idx = i * 256 + tid;
            int r = idx >> 3, cb = (idx & 7) * 8;
            async_copy16(Ab + (size_t)r * DIMSZ + k0 + cb,
                         (_Float16*)As + (size_t)(i * 256 + w * 64) * 8);
        }
        #pragma unroll
        for (int i = 0; i < 4; ++i) {
            int idx = i * 256 + tid;
            int r = idx >> 3, cb = (idx & 7) * 8;
            async_copy16(Bb + (size_t)r * DIMSZ + k0 + cb,
                         (_Float16*)Bs + (size_t)(i * 256 + w * 64) * 8);
        }
        __syncthreads();
        #pragma unroll
        for (int ks = 0; ks < 2; ++ks) {
            f16x8 af[4], bf[4];
            #pragma unroll
            for (int m = 0; m < 4; ++m)
                af[m] = *reinterpret_cast<const f16x8*>(&As[wr * 64 + m * 16 + lx][ks * 32 + g * 8]);
            #pragma unroll
            for (int n = 0; n < 4; ++n)
                bf[n] = *reinterpret_cast<const f16x8*>(&Bs[wc * 64 + n * 16 + lx][ks * 32 + g * 8]);
            #pragma unroll
            for (int m = 0; m < 4; ++m)
                #pragma unroll
                for (int n = 0; n < 4; ++n)
                    acc[m][n] = __builtin_amdgcn_mfma_f32_16x16x32_f16(af[m], bf[n], acc[m][n], 0, 0, 0);
        }
    }

    const int hcol0 = col0 + wc * 64;          // multiple of 64, one head
    const int proj  = hcol0 >> 10;
    const int hd    = (hcol0 & 1023) >> 6;
    float bsv[4];
    #pragma unroll
    for (int n = 0; n < 4; ++n) bsv[n] = bias[hcol0 + n * 16 + lx];

    #pragma unroll
    for (int m = 0; m < 4; ++m) {
        int rbase = row0 + wr * 64 + m * 16 + g * 4;
        #pragma unroll
        for (int r2 = 0; r2 < 4; ++r2) {
            int rglob = rbase + r2;
            int b = rglob >> 11, npos = rglob & (SEQLEN - 1);
            const float* rcp = ropeC + npos * 32;
            const float* rsp = ropeS + npos * 32;
            unsigned short* Orow = QKV +
                ((((size_t)proj * BATCH + b) * NHEADS + hd) * SEQLEN + npos) * HDIM;
            unsigned short* Vbase = QKV + 8388608 +
                (((size_t)b * NHEADS + hd) * HDIM) * SEQLEN + npos;
            #pragma unroll
            for (int n = 0; n < 4; ++n) {
                float v = acc[m][n][r2] + bsv[n];   // x[d], d = n*16+lx
                float o = __shfl_xor(v, 1);         // x[d^1]
                int d = n * 16 + lx;
                const float* tab = (d < 32) ? rcp : rsp;
                float Rd = tab[d & 31];             // rope[d]
                float Rp = tab[(d & 31) ^ 1];       // rope[d^1]
                float y;
                int outc;
                if (d & 1) { y = o * Rd + v * Rp; outc = (d >> 1) + 32; }
                else       { y = v * Rd - o * Rp; outc = d >> 1; }
                if (proj == 2)
                    Vbase[(size_t)outc * SEQLEN] = f16u(y);   // V^T: (b,h,d,n)
                else
                    Orow[outc] = f16u(y);
            }
        }
    }
}

// ---------------------------------------------------------------------------
// MFMA flash attention (f16). 4 waves x 16 q-rows, 64-key tiles.
// K and V^T staged via global_load_lds with PRE-SWIZZLED global source
// (linear LDS dest, XOR on read). Row-sum via MFMA ones-column (lsum);
// defer-max (THR=8 post-scale) skips rescale on the common path.
// Epilogue: -rope via shfl pairing, no LDS.
// LDS: K @0 (8KB) | V^T @8192 (8KB) | P @16384 (4x2KB)
// ---------------------------------------------------------------------------
__global__ __launch_bounds__(256) void attn_mfma_kernel(
    const unsigned short* __restrict__ QKV, const float* __restrict__ ropeC,
    const float* __restrict__ ropeS, unsigned short* __restrict__ Y)
{
    __shared__ __align__(16) unsigned char smem[24576];
    const int tid = threadIdx.x;
    const int w   = tid >> 6;
    const int l   = tid & 63;
    const int g   = l >> 4;
    const int lx  = l & 15;
    const int r8  = l >> 3;     // 0..7
    const int c8  = l & 7;      // chunk slot within row
    const int bh  = blockIdx.y;
    const int b   = bh >> 4;
    const int h   = bh & 15;
    const int q0  = blockIdx.x * 64;

    const unsigned short* Qb  = QKV + (size_t)bh * SEQLEN * HDIM;
    const unsigned short* Kb  = QKV + 4194304 + (size_t)bh * SEQLEN * HDIM;
    const unsigned short* Vtb = QKV + 8388608 + (size_t)bh * SEQLEN * HDIM;  // (d,n)

    f16x8 qf[2];
    {
        const unsigned short* src = Qb + (size_t)(q0 + w * 16 + lx) * HDIM + g * 8;
        qf[0] = *reinterpret_cast<const f16x8*>(src);
        qf[1] = *reinterpret_cast<const f16x8*>(src + 32);
    }
    f16x8 ones;
    #pragma unroll
    for (int i = 0; i < 8; ++i) ones[i] = (_Float16)1.0f;

    f32x4 oacc[4] = {};
    f32x4 lsum = {};
    float mrow[4] = {-1e30f, -1e30f, -1e30f, -1e30f};
    const int pbase = 16384 + w * 2048;

    for (int kt = 0; kt < SEQLEN / 64; ++kt) {
        const int k0 = kt * 64;
        __syncthreads();   // prev tile's reads done
        // ---- stage K and V^T: linear LDS dest, inverse-swizzled global src
        #pragma unroll
        for (int p = 0; p < 2; ++p) {
            int row = p * 32 + w * 8 + r8;          // key (K) / d (V^T)
            int ch  = c8 ^ (row & 7);
            async_copy16(Kb  + (size_t)(k0 + row) * HDIM + ch * 8,
                         smem + p * 4096 + w * 1024);
            async_copy16(Vtb + (size_t)row * SEQLEN + k0 + ch * 8,
                         smem + 8192 + p * 4096 + w * 1024);
        }
        __syncthreads();   // staged (vmcnt drained by barrier)

        // ---- QK^T: S[16q x 64key] per wave
        f32x4 sacc[4] = {};
        #pragma unroll
        for (int c = 0; c < 4; ++c) {
            int key = c * 16 + lx;
            int rowb = key * 128, sw = (key & 7) << 4;
            f16x8 b0 = *reinterpret_cast<const f16x8*>(&smem[rowb + ((g * 16) ^ sw)]);
            f16x8 b1 = *reinterpret_cast<const f16x8*>(&smem[rowb + ((64 + g * 16) ^ sw)]);
            sacc[c] = __builtin_amdgcn_mfma_f32_16x16x32_f16(qf[0], b0, sacc[c], 0, 0, 0);
            sacc[c] = __builtin_amdgcn_mfma_f32_16x16x32_f16(qf[1], b1, sacc[c], 0, 0, 0);
        }

        // ---- softmax with deferred max (THR = 64 raw = 8 post-scale)
        float lmax[4];
        #pragma unroll
        for (int r = 0; r < 4; ++r)
            lmax[r] = fmaxf(fmaxf(sacc[0][r], sacc[1][r]), fmaxf(sacc[2][r], sacc[3][r]));
        bool ok = (lmax[0] <= mrow[0] + 64.f) && (lmax[1] <= mrow[1] + 64.f) &&
                  (lmax[2] <= mrow[2] + 64.f) && (lmax[3] <= mrow[3] + 64.f);
        if (!__all((int)ok)) {
            #pragma unroll
            for (int r = 0; r < 4; ++r) {
                float mx = lmax[r];
                #pragma unroll
                for (int mm = 1; mm < 16; mm <<= 1) mx = fmaxf(mx, __shfl_xor(mx, mm));
                float mnew = fmaxf(mrow[r], mx);
                float sc = __expf((mrow[r] - mnew) * 0.125f);
                mrow[r] = mnew;
                lsum[r] *= sc;
                #pragma unroll
                for (int c2 = 0; c2 < 4; ++c2) oacc[c2][r] *= sc;
            }
        }
        #pragma unroll
        for (int c = 0; c < 4; ++c)
            #pragma unroll
            for (int r = 0; r < 4; ++r)
                sacc[c][r] = __expf((sacc[c][r] - mrow[r]) * 0.125f);

        // ---- P -> per-wave LDS (swizzled), wave-local
        #pragma unroll
        for (int c = 0; c < 4; ++c)
            #pragma unroll
            for (int r = 0; r < 4; ++r) {
                int q = g * 4 + r;
                int key = c * 16 + lx;
                *reinterpret_cast<_Float16*>(&smem[pbase + q * 128 + ((key * 2) ^ ((q & 7) << 4))]) = (_Float16)sacc[c][r];
            }
        asm volatile("s_waitcnt lgkmcnt(0)" ::: "memory");
        __builtin_amdgcn_sched_barrier(0);

        // ---- PV (+ ones-column row-sum)
        #pragma unroll
        for (int kc = 0; kc < 2; ++kc) {
            f16x8 pf = *reinterpret_cast<const f16x8*>(
                &smem[pbase + lx * 128 + ((kc * 64 + g * 16) ^ ((lx & 7) << 4))]);
            #pragma unroll
            for (int c = 0; c < 4; ++c) {
                int d = c * 16 + lx;
                f16x8 vf = *reinterpret_cast<const f16x8*>(
                    &smem[8192 + d * 128 + ((kc * 64 + g * 16) ^ ((d & 7) << 4))]);
                oacc[c] = __builtin_amdgcn_mfma_f32_16x16x32_f16(pf, vf, oacc[c], 0, 0, 0);
            }
            lsum = __builtin_amdgcn_mfma_f32_16x16x32_f16(pf, ones, lsum, 0, 0, 0);
        }
    }

    // ---- epilogue: normalize, -rope via shfl pairing, scalar f16 stores
    float inv[4];
    #pragma unroll
    for (int r = 0; r < 4; ++r) inv[r] = 1.0f / lsum[r];
    unsigned short* dstb = Y + ((size_t)b * SEQLEN + q0 + w * 16 + g * 4) * DIMSZ + h * HDIM;
    const int qrow0 = q0 + w * 16 + g * 4;
    #pragma unroll
    for (int c = 0; c < 4; ++c) {
        int d = c * 16 + lx;
        const float* tabb = (d < 32) ? ropeC : ropeS;
        #pragma unroll
        for (int r = 0; r < 4; ++r) {
            float v = oacc[c][r] * inv[r];
            float o = __shfl_xor(v, 1);
            const float* tab = tabb + (size_t)(qrow0 + r) * 32;
            float Rd = tab[d & 31];
            float Rp = tab[(d & 31) ^ 1];
            float y;
            int outc;
            if (d & 1) { y = -(o * Rd + v * Rp); outc = (d >> 1) + 32; }
            else       { y = -(v * Rd - o * Rp); outc = d >> 1; }
            dstb[(size_t)r * DIMSZ + outc] = f16u(y);
        }
    }
}

// ---------------------------------------------------------------------------
// Out GEMM: out[4096 x 1024] = Y16 @ Wo16^T + bo (f32 out)
// ---------------------------------------------------------------------------
__global__ __launch_bounds__(256) void out_gemm_kernel(
    const unsigned short* __restrict__ A, const unsigned short* __restrict__ B,
    const float* __restrict__ bias, float* __restrict__ Out)
{
    __shared__ __align__(16) _Float16 As[128][64];
    __shared__ __align__(16) _Float16 Bs[128][64];
    const int tid = threadIdx.x;
    const int w = tid >> 6, lane = tid & 63;
    const int g = lane >> 4, lx = lane & 15;
    const int wr = w >> 1, wc = w & 1;
    const int row0 = blockIdx.y * 128;
    const int col0 = blockIdx.x * 128;
    const unsigned short* Ab = A + (size_t)row0 * DIMSZ;
    const unsigned short* Bb = B + (size_t)col0 * DIMSZ;

    f32x4 acc[4][4] = {};
    for (int k0 = 0; k0 < DIMSZ; k0 += 64) {
        __syncthreads();
        #pragma unroll
        for (int i = 0; i < 4; ++i) {
            int idx = i * 256 + tid;
            int r = idx >> 3, cb = (idx & 7) * 8;
            async_copy16(Ab + (size_t)r * DIMSZ + k0 + cb,
                         (_Float16*)As + (size_t)(i * 256 + w * 64) * 8);
        }
        #pragma unroll
        for (int i = 0; i < 4; ++i) {
            int idx = i * 256 + tid;
            int r = idx >> 3, cb = (idx & 7) * 8;
            async_copy16(Bb + (size_t)r * DIMSZ + k0 + cb,
                         (_Float16*)Bs + (size_t)(i * 256 + w * 64) * 8);
        }
        __syncthreads();
        #pragma unroll
        for (int ks = 0; ks < 2; ++ks) {
            f16x8 af[4], bf[4];
            #pragma unroll
            for (int m = 0; m < 4; ++m)
                af[m] = *reinterpret_cast<const f16x8*>(&As[wr * 64 + m * 16 + lx][ks * 32 + g * 8]);
            #pragma unroll
            for (int n = 0; n < 4; ++n)
                bf[n] = *reinterpret_cast<const f16x8*>(&Bs[wc * 64 + n * 16 + lx][ks * 32 + g * 8]);
            #pragma unroll
            for (int m = 0; m < 4; ++m)
                #pragma unroll
                for (int n = 0; n < 4; ++n)
                    acc[m][n] = __builtin_amdgcn_mfma_f32_16x16x32_f16(af[m], bf[n], acc[m][n], 0, 0, 0);
        }
    }

    const int cb0 = col0 + wc * 64;
    float bsv[4];
    #pragma unroll
    for (int n = 0; n < 4; ++n) bsv[n] = bias[cb0 + n * 16 + lx];
    #pragma unroll
    for (int m = 0; m < 4; ++m) {
        int rbase = row0 + wr * 64 + m * 16 + g * 4;
        #pragma unroll
        for (int r2 = 0; r2 < 4; ++r2) {
            float* orow = Out + (size_t)(rbase + r2) * DIMSZ + cb0;
            #pragma unroll
            for (int n = 0; n < 4; ++n)
                orow[n * 16 + lx] = acc[m][n][r2] + bsv[n];
        }
    }
}

extern "C" void kernel_launch(void* const* d_in, const int* in_sizes, int n_in,
                              void* d_out, int out_size, void* d_ws, size_t ws_size,
                              hipStream_t stream) {
    const float* x  = (const float*)d_in[0];
    const float* Wq = (const float*)d_in[1];
    const float* bq = (const float*)d_in[2];
    const float* Wk = (const float*)d_in[3];
    const float* bk = (const float*)d_in[4];
    const float* Wv = (const float*)d_in[5];
    const float* bv = (const float*)d_in[6];
    const float* Wo = (const float*)d_in[7];
    const float* bo = (const float*)d_in[8];
    float* out = (float*)d_out;

    char* ws = (char*)d_ws;
    unsigned short* x16    = (unsigned short*)(ws);
    unsigned short* Wqkv16 = (unsigned short*)(ws + 8388608);
    unsigned short* Wo16   = (unsigned short*)(ws + 14680064);
    float* biasqkv         = (float*)(ws + 16777216);
    float* ropeC           = (float*)(ws + 16793600);
    float* ropeS           = (float*)(ws + 17055744);
    unsigned short* QKVw   = (unsigned short*)(ws + 17825792);
    unsigned short* Yw     = (unsigned short*)(ws + 42991616);

    dim3 blk(256);
    prep_kernel<<<dim3(2048), blk, 0, stream>>>(x, Wq, Wk, Wv, Wo, bq, bk, bv,
                                                x16, Wqkv16, Wo16, biasqkv, ropeC, ropeS);
    qkv_gemm_kernel<<<dim3(24, 32), blk, 0, stream>>>(x16, Wqkv16, biasqkv, ropeC, ropeS, QKVw);
    attn_mfma_kernel<<<dim3(SEQLEN / 64, BATCH * NHEADS), blk, 0, stream>>>(QKVw, ropeC, ropeS, Yw);
    out_gemm_kernel<<<dim3(8, 32), blk, 0, stream>>>(Yw, Wo16, bo, out);
}

// Round 8
// 182.470 us; speedup vs baseline: 2.1833x; 1.0507x over previous
//
#include <hip/hip_runtime.h>
#include <hip/hip_bf16.h>
#include <math.h>

#define NHEADS 16
#define HDIM   64
#define BATCH  2
#define SEQLEN 2048
#define DIMSZ  1024

typedef _Float16 f16x8 __attribute__((ext_vector_type(8)));
typedef float    f32x4 __attribute__((ext_vector_type(4)));
typedef unsigned short u16x8 __attribute__((ext_vector_type(8)));

__device__ __forceinline__ float rope_theta(int c) {
    int i = c & 31;
    return (float)pow(10000.0, -(double)i / 32.0);
}
__device__ __forceinline__ unsigned short f16u(float f) {
    _Float16 h = (_Float16)f;
    return *reinterpret_cast<unsigned short*>(&h);
}
__device__ __forceinline__ void async_copy16(const void* gsrc, void* lds) {
    __builtin_amdgcn_global_load_lds(
        (const __attribute__((address_space(1))) unsigned int*)gsrc,
        (__attribute__((address_space(3))) unsigned int*)lds, 16, 0, 0);
}

// ---------------------------------------------------------------------------
// prep: f32->f16 conversions (x, Wq|Wk|Wv concat, Wo), bias concat, rope tables
// ---------------------------------------------------------------------------
__global__ __launch_bounds__(256) void prep_kernel(
    const float* __restrict__ x, const float* __restrict__ Wq,
    const float* __restrict__ Wk, const float* __restrict__ Wv,
    const float* __restrict__ Wo, const float* __restrict__ bq,
    const float* __restrict__ bk, const float* __restrict__ bv,
    unsigned short* __restrict__ x16, unsigned short* __restrict__ Wqkv16,
    unsigned short* __restrict__ Wo16, float* __restrict__ biasqkv,
    float* __restrict__ ropeC, float* __restrict__ ropeS)
{
    const int NV = (4194304 + 4 * 1048576) / 8;   // 1,048,576 vec8 chunks
    int gid = blockIdx.x * 256 + threadIdx.x;
    for (int i = gid; i < NV; i += gridDim.x * 256) {
        long e = (long)i * 8;
        const float* src; unsigned short* dst; long off;
        if (e < 4194304)      { src = x;  dst = x16;              off = e; }
        else if (e < 5242880) { src = Wq; dst = Wqkv16;           off = e - 4194304; }
        else if (e < 6291456) { src = Wk; dst = Wqkv16 + 1048576; off = e - 5242880; }
        else if (e < 7340032) { src = Wv; dst = Wqkv16 + 2097152; off = e - 6291456; }
        else                  { src = Wo; dst = Wo16;             off = e - 7340032; }
        float4 v0 = *reinterpret_cast<const float4*>(src + off);
        float4 v1 = *reinterpret_cast<const float4*>(src + off + 4);
        u16x8 o;
        o[0] = f16u(v0.x); o[1] = f16u(v0.y); o[2] = f16u(v0.z); o[3] = f16u(v0.w);
        o[4] = f16u(v1.x); o[5] = f16u(v1.y); o[6] = f16u(v1.z); o[7] = f16u(v1.w);
        *reinterpret_cast<u16x8*>(dst + off) = o;
    }
    if (gid < 65536) {
        int npos = gid >> 5, j = gid & 31;
        float f = (float)npos * rope_theta(j);
        ropeC[gid] = cosf(f);
        ropeS[gid] = sinf(f);
    }
    if (gid < 3072) {
        biasqkv[gid] = gid < 1024 ? bq[gid] : (gid < 2048 ? bk[gid - 1024] : bv[gid - 2048]);
    }
}

// ---------------------------------------------------------------------------
// Fused QKV GEMM + bias + (non-standard) rope.
//   Q, K -> (b,h,n,d) f16;  V -> TRANSPOSED (b,h,d,n) f16, written via an
//   LDS transpose (T[128 d][136] f16, stride 136 >= 128 cols, 16B-aligned
//   rows: 136*2=272=17*16) so global stores are n-contiguous.
//   out[p]    = x[2p]*rope[2p]   - x[2p+1]*rope[2p+1]
//   out[p+32] = x[2p]*rope[2p+1] + x[2p+1]*rope[2p]
// where rope = [cos(th_0..31) | sin(th_0..31)] per position.
// ---------------------------------------------------------------------------
__global__ __launch_bounds__(256) void qkv_gemm_kernel(
    const unsigned short* __restrict__ A, const unsigned short* __restrict__ B,
    const float* __restrict__ bias, const float* __restrict__ ropeC,
    const float* __restrict__ ropeS, unsigned short* __restrict__ QKV)
{
    __shared__ __align__(16) unsigned char smem[34816];   // max(As+Bs 32768, T 34816)
    _Float16 (*As)[64] = (_Float16(*)[64])smem;            // [128][64]
    _Float16 (*Bs)[64] = (_Float16(*)[64])(smem + 16384);  // [128][64]
    const int tid = threadIdx.x;
    const int w = tid >> 6, lane = tid & 63;
    const int g = lane >> 4, lx = lane & 15;
    const int wr = w >> 1, wc = w & 1;
    const int row0 = blockIdx.y * 128;
    const int col0 = blockIdx.x * 128;
    const unsigned short* Ab = A + (size_t)row0 * DIMSZ;
    const unsigned short* Bb = B + (size_t)col0 * DIMSZ;

    f32x4 acc[4][4] = {};
    for (int k0 = 0; k0 < DIMSZ; k0 += 64) {
        __syncthreads();
        #pragma unroll
        for (int i = 0; i < 4; ++i) {
            int idx = i * 256 + tid;
            int r = idx >> 3, cb = (idx & 7) * 8;
            async_copy16(Ab + (size_t)r * DIMSZ + k0 + cb,
                         (_Float16*)As + (size_t)(i * 256 + w * 64) * 8);
        }
        #pragma unroll
        for (int i = 0; i < 4; ++i) {
            int idx = i * 256 + tid;
            int r = idx >> 3, cb = (idx & 7) * 8;
            async_copy16(Bb + (size_t)r * DIMSZ + k0 + cb,
                         (_Float16*)Bs + (size_t)(i * 256 + w * 64) * 8);
        }
        __syncthreads();
        #pragma unroll
        for (int ks = 0; ks < 2; ++ks) {
            f16x8 af[4], bf[4];
            #pragma unroll
            for (int m = 0; m < 4; ++m)
                af[m] = *reinterpret_cast<const f16x8*>(&As[wr * 64 + m * 16 + lx][ks * 32 + g * 8]);
            #pragma unroll
            for (int n = 0; n < 4; ++n)
                bf[n] = *reinterpret_cast<const f16x8*>(&Bs[wc * 64 + n * 16 + lx][ks * 32 + g * 8]);
            #pragma unroll
            for (int m = 0; m < 4; ++m)
                #pragma unroll
                for (int n = 0; n < 4; ++n)
                    acc[m][n] = __builtin_amdgcn_mfma_f32_16x16x32_f16(af[m], bf[n], acc[m][n], 0, 0, 0);
        }
    }

    const int hcol0 = col0 + wc * 64;          // multiple of 64, one head
    const int proj  = hcol0 >> 10;             // runtime block-uniform (col0 mult of 128)
    const int hd    = (hcol0 & 1023) >> 6;
    float bsv[4];
    #pragma unroll
    for (int n = 0; n < 4; ++n) bsv[n] = bias[hcol0 + n * 16 + lx];

    if (proj == 2) {
        // ---- V: rope -> LDS transpose T[d][rlocal] -> coalesced (b,h,d,n) stores
        __syncthreads();
        _Float16* T = (_Float16*)smem;   // [128][136] = 34816B
        #pragma unroll
        for (int m = 0; m < 4; ++m) {
            int rl0 = wr * 64 + m * 16 + g * 4;
            #pragma unroll
            for (int r2 = 0; r2 < 4; ++r2) {
                int rlocal = rl0 + r2;
                int npos = (row0 + rlocal) & (SEQLEN - 1);
                const float* rcp = ropeC + npos * 32;
                const float* rsp = ropeS + npos * 32;
                #pragma unroll
                for (int n = 0; n < 4; ++n) {
                    float v = acc[m][n][r2] + bsv[n];
                    float o = __shfl_xor(v, 1);
                    int d = n * 16 + lx;
                    const float* tab = (d < 32) ? rcp : rsp;
                    float Rd = tab[d & 31];
                    float Rp = tab[(d & 31) ^ 1];
                    float y; int outc;
                    if (d & 1) { y = o * Rd + v * Rp; outc = (d >> 1) + 32; }
                    else       { y = v * Rd - o * Rp; outc = d >> 1; }
                    T[(wc * 64 + outc) * 136 + rlocal] = (_Float16)y;
                }
            }
        }
        __syncthreads();
        int b = row0 >> 11, npos0 = row0 & (SEQLEN - 1);
        int hd0 = (col0 & 1023) >> 6;
        #pragma unroll
        for (int i2 = 0; i2 < 8; ++i2) {
            int trow = w * 32 + i2 * 4 + g;
            int head = hd0 + (trow >> 6);
            int outd = trow & 63;
            f16x8 val = *reinterpret_cast<const f16x8*>(&T[trow * 136 + lx * 8]);
            *reinterpret_cast<f16x8*>(QKV + 8388608 +
                (((size_t)b * NHEADS + head) * HDIM + outd) * SEQLEN + npos0 + lx * 8) = val;
        }
    } else {
        #pragma unroll
        for (int m = 0; m < 4; ++m) {
            int rbase = row0 + wr * 64 + m * 16 + g * 4;
            #pragma unroll
            for (int r2 = 0; r2 < 4; ++r2) {
                int rglob = rbase + r2;
                int b = rglob >> 11, npos = rglob & (SEQLEN - 1);
                const float* rcp = ropeC + npos * 32;
                const float* rsp = ropeS + npos * 32;
                unsigned short* Orow = QKV +
                    ((((size_t)proj * BATCH + b) * NHEADS + hd) * SEQLEN + npos) * HDIM;
                #pragma unroll
                for (int n = 0; n < 4; ++n) {
                    float v = acc[m][n][r2] + bsv[n];   // x[d], d = n*16+lx
                    float o = __shfl_xor(v, 1);         // x[d^1]
                    int d = n * 16 + lx;
                    const float* tab = (d < 32) ? rcp : rsp;
                    float Rd = tab[d & 31];             // rope[d]
                    float Rp = tab[(d & 31) ^ 1];       // rope[d^1]
                    float y; int outc;
                    if (d & 1) { y = o * Rd + v * Rp; outc = (d >> 1) + 32; }
                    else       { y = v * Rd - o * Rp; outc = d >> 1; }
                    Orow[outc] = f16u(y);
                }
            }
        }
    }
}

// ---------------------------------------------------------------------------
// MFMA flash attention (f16). 4 waves x 16 q-rows, 64-key tiles.
// XCD-aware flat grid: same (b,h) stays on one XCD (K/V L2-resident).
// K and V^T staged via global_load_lds with pre-swizzled global source.
// Row-sum via MFMA ones-column; defer-max skips rescale on the common path.
// LDS: K @0 (8KB) | V^T @8192 (8KB) | P @16384 (4x2KB)
// ---------------------------------------------------------------------------
__global__ __launch_bounds__(256) void attn_mfma_kernel(
    const unsigned short* __restrict__ QKV, const float* __restrict__ ropeC,
    const float* __restrict__ ropeS, unsigned short* __restrict__ Y)
{
    __shared__ __align__(16) unsigned char smem[24576];
    const int tid = threadIdx.x;
    const int w   = tid >> 6;
    const int l   = tid & 63;
    const int g   = l >> 4;
    const int lx  = l & 15;
    const int r8  = l >> 3;     // 0..7
    const int c8  = l & 7;      // chunk slot within row
    const int fb  = blockIdx.x;
    const int xcd = fb & 7, jj = fb >> 3;
    const int bh  = xcd * 4 + (jj & 3);       // 4 bh per XCD -> K/V L2-local
    const int b   = bh >> 4;
    const int h   = bh & 15;
    const int q0  = (jj >> 2) * 64;

    const unsigned short* Qb  = QKV + (size_t)bh * SEQLEN * HDIM;
    const unsigned short* Kb  = QKV + 4194304 + (size_t)bh * SEQLEN * HDIM;
    const unsigned short* Vtb = QKV + 8388608 + (size_t)bh * SEQLEN * HDIM;  // (d,n)

    f16x8 qf[2];
    {
        const unsigned short* src = Qb + (size_t)(q0 + w * 16 + lx) * HDIM + g * 8;
        qf[0] = *reinterpret_cast<const f16x8*>(src);
        qf[1] = *reinterpret_cast<const f16x8*>(src + 32);
    }
    f16x8 ones;
    #pragma unroll
    for (int i = 0; i < 8; ++i) ones[i] = (_Float16)1.0f;

    f32x4 oacc[4] = {};
    f32x4 lsum = {};
    float mrow[4] = {-1e30f, -1e30f, -1e30f, -1e30f};
    const int pbase = 16384 + w * 2048;

    for (int kt = 0; kt < SEQLEN / 64; ++kt) {
        const int k0 = kt * 64;
        __syncthreads();   // prev tile's reads done
        // ---- stage K and V^T: linear LDS dest, inverse-swizzled global src
        #pragma unroll
        for (int p = 0; p < 2; ++p) {
            int row = p * 32 + w * 8 + r8;          // key (K) / d (V^T)
            int ch  = c8 ^ (row & 7);
            async_copy16(Kb  + (size_t)(k0 + row) * HDIM + ch * 8,
                         smem + p * 4096 + w * 1024);
            async_copy16(Vtb + (size_t)row * SEQLEN + k0 + ch * 8,
                         smem + 8192 + p * 4096 + w * 1024);
        }
        __syncthreads();   // staged (vmcnt drained by barrier)

        // ---- QK^T: S[16q x 64key] per wave
        f32x4 sacc[4] = {};
        #pragma unroll
        for (int c = 0; c < 4; ++c) {
            int key = c * 16 + lx;
            int rowb = key * 128, sw = (key & 7) << 4;
            f16x8 b0 = *reinterpret_cast<const f16x8*>(&smem[rowb + ((g * 16) ^ sw)]);
            f16x8 b1 = *reinterpret_cast<const f16x8*>(&smem[rowb + ((64 + g * 16) ^ sw)]);
            sacc[c] = __builtin_amdgcn_mfma_f32_16x16x32_f16(qf[0], b0, sacc[c], 0, 0, 0);
            sacc[c] = __builtin_amdgcn_mfma_f32_16x16x32_f16(qf[1], b1, sacc[c], 0, 0, 0);
        }

        // ---- softmax with deferred max (THR = 64 raw = 8 post-scale)
        float lmax[4];
        #pragma unroll
        for (int r = 0; r < 4; ++r)
            lmax[r] = fmaxf(fmaxf(sacc[0][r], sacc[1][r]), fmaxf(sacc[2][r], sacc[3][r]));
        bool ok = (lmax[0] <= mrow[0] + 64.f) && (lmax[1] <= mrow[1] + 64.f) &&
                  (lmax[2] <= mrow[2] + 64.f) && (lmax[3] <= mrow[3] + 64.f);
        if (!__all((int)ok)) {
            #pragma unroll
            for (int r = 0; r < 4; ++r) {
                float mx = lmax[r];
                #pragma unroll
                for (int mm = 1; mm < 16; mm <<= 1) mx = fmaxf(mx, __shfl_xor(mx, mm));
                float mnew = fmaxf(mrow[r], mx);
                float sc = __expf((mrow[r] - mnew) * 0.125f);
                mrow[r] = mnew;
                lsum[r] *= sc;
                #pragma unroll
                for (int c2 = 0; c2 < 4; ++c2) oacc[c2][r] *= sc;
            }
        }
        #pragma unroll
        for (int c = 0; c < 4; ++c)
            #pragma unroll
            for (int r = 0; r < 4; ++r)
                sacc[c][r] = __expf((sacc[c][r] - mrow[r]) * 0.125f);

        // ---- P -> per-wave LDS (swizzled), wave-local
        #pragma unroll
        for (int c = 0; c < 4; ++c)
            #pragma unroll
            for (int r = 0; r < 4; ++r) {
                int q = g * 4 + r;
                int key = c * 16 + lx;
                *reinterpret_cast<_Float16*>(&smem[pbase + q * 128 + ((key * 2) ^ ((q & 7) << 4))]) = (_Float16)sacc[c][r];
            }
        asm volatile("s_waitcnt lgkmcnt(0)" ::: "memory");
        __builtin_amdgcn_sched_barrier(0);

        // ---- PV (+ ones-column row-sum)
        #pragma unroll
        for (int kc = 0; kc < 2; ++kc) {
            f16x8 pf = *reinterpret_cast<const f16x8*>(
                &smem[pbase + lx * 128 + ((kc * 64 + g * 16) ^ ((lx & 7) << 4))]);
            #pragma unroll
            for (int c = 0; c < 4; ++c) {
                int d = c * 16 + lx;
                f16x8 vf = *reinterpret_cast<const f16x8*>(
                    &smem[8192 + d * 128 + ((kc * 64 + g * 16) ^ ((d & 7) << 4))]);
                oacc[c] = __builtin_amdgcn_mfma_f32_16x16x32_f16(pf, vf, oacc[c], 0, 0, 0);
            }
            lsum = __builtin_amdgcn_mfma_f32_16x16x32_f16(pf, ones, lsum, 0, 0, 0);
        }
    }

    // ---- epilogue: normalize, -rope via shfl pairing, scalar f16 stores
    float inv[4];
    #pragma unroll
    for (int r = 0; r < 4; ++r) inv[r] = 1.0f / lsum[r];
    unsigned short* dstb = Y + ((size_t)b * SEQLEN + q0 + w * 16 + g * 4) * DIMSZ + h * HDIM;
    const int qrow0 = q0 + w * 16 + g * 4;
    #pragma unroll
    for (int c = 0; c < 4; ++c) {
        int d = c * 16 + lx;
        const float* tabb = (d < 32) ? ropeC : ropeS;
        #pragma unroll
        for (int r = 0; r < 4; ++r) {
            float v = oacc[c][r] * inv[r];
            float o = __shfl_xor(v, 1);
            const float* tab = tabb + (size_t)(qrow0 + r) * 32;
            float Rd = tab[d & 31];
            float Rp = tab[(d & 31) ^ 1];
            float y;
            int outc;
            if (d & 1) { y = -(o * Rd + v * Rp); outc = (d >> 1) + 32; }
            else       { y = -(v * Rd - o * Rp); outc = d >> 1; }
            dstb[(size_t)r * DIMSZ + outc] = f16u(y);
        }
    }
}

// ---------------------------------------------------------------------------
// Out GEMM: out[4096 x 1024] = Y16 @ Wo16^T + bo (f32 out)
// ---------------------------------------------------------------------------
__global__ __launch_bounds__(256) void out_gemm_kernel(
    const unsigned short* __restrict__ A, const unsigned short* __restrict__ B,
    const float* __restrict__ bias, float* __restrict__ Out)
{
    __shared__ __align__(16) _Float16 As[128][64];
    __shared__ __align__(16) _Float16 Bs[128][64];
    const int tid = threadIdx.x;
    const int w = tid >> 6, lane = tid & 63;
    const int g = lane >> 4, lx = lane & 15;
    const int wr = w >> 1, wc = w & 1;
    const int row0 = blockIdx.y * 128;
    const int col0 = blockIdx.x * 128;
    const unsigned short* Ab = A + (size_t)row0 * DIMSZ;
    const unsigned short* Bb = B + (size_t)col0 * DIMSZ;

    f32x4 acc[4][4] = {};
    for (int k0 = 0; k0 < DIMSZ; k0 += 64) {
        __syncthreads();
        #pragma unroll
        for (int i = 0; i < 4; ++i) {
            int idx = i * 256 + tid;
            int r = idx >> 3, cb = (idx & 7) * 8;
            async_copy16(Ab + (size_t)r * DIMSZ + k0 + cb,
                         (_Float16*)As + (size_t)(i * 256 + w * 64) * 8);
        }
        #pragma unroll
        for (int i = 0; i < 4; ++i) {
            int idx = i * 256 + tid;
            int r = idx >> 3, cb = (idx & 7) * 8;
            async_copy16(Bb + (size_t)r * DIMSZ + k0 + cb,
                         (_Float16*)Bs + (size_t)(i * 256 + w * 64) * 8);
        }
        __syncthreads();
        #pragma unroll
        for (int ks = 0; ks < 2; ++ks) {
            f16x8 af[4], bf[4];
            #pragma unroll
            for (int m = 0; m < 4; ++m)
                af[m] = *reinterpret_cast<const f16x8*>(&As[wr * 64 + m * 16 + lx][ks * 32 + g * 8]);
            #pragma unroll
            for (int n = 0; n < 4; ++n)
                bf[n] = *reinterpret_cast<const f16x8*>(&Bs[wc * 64 + n * 16 + lx][ks * 32 + g * 8]);
            #pragma unroll
            for (int m = 0; m < 4; ++m)
                #pragma unroll
                for (int n = 0; n < 4; ++n)
                    acc[m][n] = __builtin_amdgcn_mfma_f32_16x16x32_f16(af[m], bf[n], acc[m][n], 0, 0, 0);
        }
    }

    const int cb0 = col0 + wc * 64;
    float bsv[4];
    #pragma unroll
    for (int n = 0; n < 4; ++n) bsv[n] = bias[cb0 + n * 16 + lx];
    #pragma unroll
    for (int m = 0; m < 4; ++m) {
        int rbase = row0 + wr * 64 + m * 16 + g * 4;
        #pragma unroll
        for (int r2 = 0; r2 < 4; ++r2) {
            float* orow = Out + (size_t)(rbase + r2) * DIMSZ + cb0;
            #pragma unroll
            for (int n = 0; n < 4; ++n)
                orow[n * 16 + lx] = acc[m][n][r2] + bsv[n];
        }
    }
}

extern "C" void kernel_launch(void* const* d_in, const int* in_sizes, int n_in,
                              void* d_out, int out_size, void* d_ws, size_t ws_size,
                              hipStream_t stream) {
    const float* x  = (const float*)d_in[0];
    const float* Wq = (const float*)d_in[1];
    const float* bq = (const float*)d_in[2];
    const float* Wk = (const float*)d_in[3];
    const float* bk = (const float*)d_in[4];
    const float* Wv = (const float*)d_in[5];
    const float* bv = (const float*)d_in[6];
    const float* Wo = (const float*)d_in[7];
    const float* bo = (const float*)d_in[8];
    float* out = (float*)d_out;

    char* ws = (char*)d_ws;
    unsigned short* x16    = (unsigned short*)(ws);
    unsigned short* Wqkv16 = (unsigned short*)(ws + 8388608);
    unsigned short* Wo16   = (unsigned short*)(ws + 14680064);
    float* biasqkv         = (float*)(ws + 16777216);
    float* ropeC           = (float*)(ws + 16793600);
    float* ropeS           = (float*)(ws + 17055744);
    unsigned short* QKVw   = (unsigned short*)(ws + 17825792);
    unsigned short* Yw     = (unsigned short*)(ws + 42991616);

    dim3 blk(256);
    prep_kernel<<<dim3(2048), blk, 0, stream>>>(x, Wq, Wk, Wv, Wo, bq, bk, bv,
                                                x16, Wqkv16, Wo16, biasqkv, ropeC, ropeS);
    qkv_gemm_kernel<<<dim3(24, 32), blk, 0, stream>>>(x16, Wqkv16, biasqkv, ropeC, ropeS, QKVw);
    attn_mfma_kernel<<<dim3(1024), blk, 0, stream>>>(QKVw, ropeC, ropeS, Yw);
    out_gemm_kernel<<<dim3(8, 32), blk, 0, stream>>>(Yw, Wo16, bo, out);
}